// Round 4
// baseline (212.098 us; speedup 1.0000x reference)
//
#include <hip/hip_runtime.h>
#include <hip/hip_bf16.h>
#include <stdint.h>

// ---------------------------------------------------------------------------
// Loss_29592324669863, round 4.
//  - norm rows -> bf16 (+ zero-init of hacc/fbuf)
//  - fused Gram kernel: 128x128 tile, 4 waves, BK=32, DOUBLE-BUFFERED with
//    counted vmcnt(4) pipeline (raw s_barrier, never drain-0 mid-loop),
//    setprio around MFMA. class/cross triangular symmetry; epilogue writes
//    CONFLICT-FREE float2 partial slots (no global atomics).
//  - finalize1 (48 blk): per-row slot-sum -> -log -> block partial
//  - finalize2 (1 blk): combine -> out[3]
// ---------------------------------------------------------------------------

typedef __attribute__((ext_vector_type(8))) short bf16x8;   // 8 bf16 = 4 VGPR
typedef __attribute__((ext_vector_type(4))) float f32x4;

__device__ inline void gload_lds16(const void* g, void* l) {
  __builtin_amdgcn_global_load_lds(
      (__attribute__((address_space(1))) void*)g,
      (__attribute__((address_space(3))) void*)l, 16, 0, 0);
}

__device__ inline void barrier_raw() {
  asm volatile("" ::: "memory");
  __builtin_amdgcn_s_barrier();
  asm volatile("" ::: "memory");
}

__device__ inline unsigned short f2bf(float x) {  // RNE f32->bf16
  unsigned int u = __builtin_bit_cast(unsigned int, x);
  u = (u + 0x7fffu + ((u >> 16) & 1u)) >> 16;
  return (unsigned short)u;
}

// ---------------------------------------------------------------------------
__global__ __launch_bounds__(256) void norm_kernel(
    const float* __restrict__ LE, const float* __restrict__ FZ,
    const float* __restrict__ SE, const float* __restrict__ LM,
    unsigned short* __restrict__ An, unsigned short* __restrict__ Fn,
    unsigned short* __restrict__ Sn, unsigned short* __restrict__ Ln,
    float* __restrict__ zbuf) {
  const int tid = threadIdx.x;
  if (blockIdx.x == 0 && tid < 49) zbuf[tid] = 0.f;  // hacc + fbuf[48]

  const int wid = tid >> 6, lane = tid & 63;
  const int row = blockIdx.x * 4 + wid;

  const float* src;
  unsigned short* dst;
  int r;
  if (row < 4096)       { src = LE; dst = An; r = row; }
  else if (row < 12288) { src = FZ; dst = Fn; r = row - 4096; }
  else if (row < 16384) { src = SE; dst = Sn; r = row - 12288; }
  else                  { src = LM; dst = Ln; r = row - 16384; }

  const float4 v = *(const float4*)(src + (size_t)r * 256 + lane * 4);
  float ss = v.x * v.x + v.y * v.y + v.z * v.z + v.w * v.w;
#pragma unroll
  for (int m = 1; m < 64; m <<= 1) ss += __shfl_xor(ss, m);
  const float scale = 1.0f / fmaxf(sqrtf(ss), 1e-8f);

  ushort4 o;
  o.x = f2bf(v.x * scale);
  o.y = f2bf(v.y * scale);
  o.z = f2bf(v.z * scale);
  o.w = f2bf(v.w * scale);
  *(ushort4*)(dst + (size_t)r * 256 + lane * 4) = o;
}

// ---------------------------------------------------------------------------
__device__ inline void tri_decode(int t, int nb, int& rb, int& cb) {
  int r = 0;
  while (t >= nb - r) { t -= nb - r; ++r; }
  rb = r;
  cb = r + t;
}

// ---------------------------------------------------------------------------
// Fused Gram kernel: 128x128 tile, 4 waves (2x2), BK=32, dbuf counted-vmcnt.
// LDS 16B-granule swizzle: phys granule = logical ^ (row&3), applied on the
// pre-swizzled GLOBAL source (LDS write linear) and on ds_read addresses.
// ---------------------------------------------------------------------------
__global__ __launch_bounds__(256, 4) void fused_sim(
    const unsigned short* __restrict__ An, const unsigned short* __restrict__ Fn,
    const unsigned short* __restrict__ Sn, const unsigned short* __restrict__ Ln,
    const int* __restrict__ labels,
    const float* __restrict__ tp, const float* __restrict__ xip,
    float2* __restrict__ Pc,   // [32 slots][4096 rows] (num,den)
    float2* __restrict__ Px,   // [64 slots][8192 rows]
    float* __restrict__ hacc) {
  __shared__ __align__(16) char Ab[2][8192];   // [buf][128 rows x 64B]
  __shared__ __align__(16) char Bb[2][8192];
  __shared__ int lrS[128], lcS[128];

  // XCD swizzle: 3632 = 8 * 454 (bijective)
  const int hw = blockIdx.x;
  const int bid = (hw & 7) * 454 + (hw >> 3);

  int mode, rb, cb;
  const unsigned short *X, *Y;
  if (bid < 528) {            // class: tri over 32x32 panels
    mode = 0; tri_decode(bid, 32, rb, cb); X = An; Y = An;
  } else if (bid < 2608) {    // cross: tri over 64x64 panels
    mode = 1; tri_decode(bid - 528, 64, rb, cb); X = Fn; Y = Fn;
  } else {                    // hash: full 32x32
    mode = 2; const int t = bid - 2608; rb = t >> 5; cb = t & 31;
    X = Sn; Y = Ln;
  }

  const int tid = threadIdx.x;
  const int lane = tid & 63, wid = tid >> 6;
  const int wr = wid >> 1, wc = wid & 1;
  const int g = lane >> 4, c = lane & 15;

  // label for my slot (1 uniform VMEM load per thread; consumed at kk=0)
  const int mylab = labels[(tid < 128 ? rb * 128 + tid : cb * 128 + tid - 128) & 4095];

  f32x4 acc[4][4];
  const f32x4 zero = {0.f, 0.f, 0.f, 0.f};
#pragma unroll
  for (int m = 0; m < 4; ++m)
#pragma unroll
    for (int n = 0; n < 4; ++n) acc[m][n] = zero;

  // staging geometry: per kk window (32 cols = 64B) stage 8KB A + 8KB B,
  // 4 gload_lds16 per thread (A t0,t1 + B t0,t1). LDS linear, src swizzled.
  const int srow = tid >> 2;                      // 0..63
  const int sgl = (tid & 3) ^ (srow & 3);         // swizzled source granule
  const char* xs = (const char*)X + ((size_t)rb * 128 + srow) * 512 + sgl * 16;
  const char* ys = (const char*)Y + ((size_t)cb * 128 + srow) * 512 + sgl * 16;
  char* la = (char*)Ab + wid * 1024;              // wave-uniform LDS bases
  char* lb = (char*)Bb + wid * 1024;

#define STAGE(KK, I)                                                   \
  {                                                                    \
    gload_lds16(xs + (KK) * 64,         la + (I) * 8192);              \
    gload_lds16(xs + 32768 + (KK) * 64, la + (I) * 8192 + 4096);       \
    gload_lds16(ys + (KK) * 64,         lb + (I) * 8192);              \
    gload_lds16(ys + 32768 + (KK) * 64, lb + (I) * 8192 + 4096);       \
  }

  STAGE(0, 0);
  STAGE(1, 1);   // 8 loads/thread outstanding

  // fragment geometry: row = (wr|wc)*64 + m*16 + c, byte = row*64 + phys*16,
  // phys = g ^ (row&3) = g ^ (c&3)
  const int pg = (g ^ (c & 3)) * 16;
  const char* aB = (const char*)Ab + (wr * 64 + c) * 64 + pg;
  const char* bB = (const char*)Bb + (wc * 64 + c) * 64 + pg;

#pragma unroll
  for (int kk = 0; kk < 8; ++kk) {
    if (kk < 7) asm volatile("s_waitcnt vmcnt(4)" ::: "memory");
    else        asm volatile("s_waitcnt vmcnt(0)" ::: "memory");
    barrier_raw();                    // current buffer ready for all waves
    if (kk == 0) {                    // park labels in LDS (read in epilogue)
      if (tid < 128) lrS[tid] = mylab;
      else           lcS[tid - 128] = mylab;
    }
    const int bo = (kk & 1) * 8192;
    bf16x8 af[4], bg[4];
#pragma unroll
    for (int m = 0; m < 4; ++m) af[m] = *(const bf16x8*)(aB + bo + m * 1024);
#pragma unroll
    for (int n = 0; n < 4; ++n) bg[n] = *(const bf16x8*)(bB + bo + n * 1024);
    __builtin_amdgcn_s_setprio(1);
#pragma unroll
    for (int m = 0; m < 4; ++m)
#pragma unroll
      for (int n = 0; n < 4; ++n)
        acc[m][n] = __builtin_amdgcn_mfma_f32_16x16x32_bf16(
            af[m], bg[n], acc[m][n], 0, 0, 0);
    __builtin_amdgcn_s_setprio(0);
    barrier_raw();                    // all waves done reading this buffer
    if (kk < 6) STAGE(kk + 2, kk & 1);
  }
#undef STAGE

  // ---- epilogue; C/D layout: col = c, row = g*4 + reg ----
  float* sc = (float*)Ab;   // 4KB scratch overlay (safe after final barrier)
  if (mode < 2) {
    const float invt = 1.0f / tp[0];
    const bool docol = (rb != cb);
    float2* Pp = (mode == 0) ? Pc : Px;
    const int NR = (mode == 0) ? 4096 : 8192;
    int collab[4];
#pragma unroll
    for (int n = 0; n < 4; ++n) collab[n] = lcS[wc * 64 + n * 16 + c];

    float* rowN = sc, *rowD = sc + 256, *colN = sc + 512, *colD = sc + 768;
    float cn[4] = {0.f, 0.f, 0.f, 0.f}, cd[4] = {0.f, 0.f, 0.f, 0.f};
    float rn[16], rd[16];
#pragma unroll
    for (int m = 0; m < 4; ++m) {
#pragma unroll
      for (int reg = 0; reg < 4; ++reg) {
        const int rlab = lrS[wr * 64 + m * 16 + g * 4 + reg];
        float pn = 0.f, pd = 0.f;
#pragma unroll
        for (int n = 0; n < 4; ++n) {
          float e = __expf(acc[m][n][reg] * invt);
          if (mode == 0) e = fminf(e, 1e10f);
          pd += e;
          const float en = (rlab == collab[n]) ? e : 0.f;
          pn += en;
          cd[n] += e;
          cn[n] += en;
        }
#pragma unroll
        for (int msk = 1; msk < 16; msk <<= 1) {
          pn += __shfl_xor(pn, msk);
          pd += __shfl_xor(pd, msk);
        }
        rn[m * 4 + reg] = pn;
        rd[m * 4 + reg] = pd;
      }
    }
    if (c == 0) {
#pragma unroll
      for (int m = 0; m < 4; ++m)
#pragma unroll
        for (int reg = 0; reg < 4; ++reg) {
          const int rloc = wr * 64 + m * 16 + g * 4 + reg;
          rowN[wc * 128 + rloc] = rn[m * 4 + reg];
          rowD[wc * 128 + rloc] = rd[m * 4 + reg];
        }
    }
#pragma unroll
    for (int n = 0; n < 4; ++n) {
      float a = cn[n], b = cd[n];
      a += __shfl_xor(a, 16); b += __shfl_xor(b, 16);
      a += __shfl_xor(a, 32); b += __shfl_xor(b, 32);
      if (g == 0) {
        colN[wr * 128 + wc * 64 + n * 16 + c] = a;
        colD[wr * 128 + wc * 64 + n * 16 + c] = b;
      }
    }
    __syncthreads();
    // conflict-free partial slots: row-contrib -> slot cb, col -> slot rb
    if (tid < 128) {
      Pp[(size_t)cb * NR + rb * 128 + tid] =
          make_float2(rowN[tid] + rowN[128 + tid], rowD[tid] + rowD[128 + tid]);
    } else if (docol) {
      const int t2 = tid - 128;
      Pp[(size_t)rb * NR + cb * 128 + t2] =
          make_float2(colN[t2] + colN[128 + t2], colD[t2] + colD[128 + t2]);
    }
  } else {
    const float xi = xip[0];
    int collab[4];
#pragma unroll
    for (int n = 0; n < 4; ++n) collab[n] = lcS[wc * 64 + n * 16 + c];
    float part = 0.f;
#pragma unroll
    for (int m = 0; m < 4; ++m)
#pragma unroll
      for (int reg = 0; reg < 4; ++reg) {
        const int rlab = lrS[wr * 64 + m * 16 + g * 4 + reg];
#pragma unroll
        for (int n = 0; n < 4; ++n) {
          const float cs = acc[m][n][reg];
          const float Dm = (1.0f - cs) * 0.5f;
          const float u = fmaxf(xi - Dm, 0.0f);
          part += (rlab == collab[n]) ? Dm * Dm : u * u;
        }
      }
#pragma unroll
    for (int msk = 1; msk < 64; msk <<= 1) part += __shfl_xor(part, msk);
    if (lane == 0) sc[wid] = part;
    __syncthreads();
    if (tid == 0) atomicAdd(hacc, sc[0] + sc[1] + sc[2] + sc[3]);
  }
}

// ---------------------------------------------------------------------------
// finalize1: blocks 0..15 -> class rows, 16..47 -> cross rows.
__global__ __launch_bounds__(256) void finalize1(
    const float2* __restrict__ Pc, const float2* __restrict__ Px,
    float* __restrict__ fbuf) {
  const int b = blockIdx.x, tid = threadIdx.x;
  const float2* P;
  int nslots, NR, row;
  if (b < 16) { P = Pc; nslots = 32; NR = 4096; row = b * 256 + tid; }
  else        { P = Px; nslots = 64; NR = 8192; row = (b - 16) * 256 + tid; }
  float n = 0.f, d = 0.f;
  for (int s = 0; s < nslots; ++s) {
    const float2 v = P[(size_t)s * NR + row];
    n += v.x;
    d += v.y;
  }
  float val = -logf(n / fmaxf(d, 1e-10f));
#pragma unroll
  for (int m = 1; m < 64; m <<= 1) val += __shfl_xor(val, m);
  __shared__ float r[4];
  if ((tid & 63) == 0) r[tid >> 6] = val;
  __syncthreads();
  if (tid == 0) fbuf[b] = r[0] + r[1] + r[2] + r[3];
}

__global__ __launch_bounds__(64) void finalize2(
    const float* __restrict__ fbuf, const float* __restrict__ hacc,
    float* __restrict__ out) {
  const int lane = threadIdx.x;
  float a = (lane < 16) ? fbuf[lane] : 0.f;
  float b = (lane < 32) ? fbuf[16 + lane] : 0.f;  // lanes 0..31 -> 16..47
#pragma unroll
  for (int m = 1; m < 64; m <<= 1) {
    a += __shfl_xor(a, m);
    b += __shfl_xor(b, m);
  }
  if (lane == 0) {
    out[0] = a / 4096.0f;
    out[1] = b / 8192.0f;
    out[2] = hacc[0] / (4096.0f * 4096.0f);
  }
}

// ---------------------------------------------------------------------------
extern "C" void kernel_launch(void* const* d_in, const int* in_sizes, int n_in,
                              void* d_out, int out_size, void* d_ws,
                              size_t ws_size, hipStream_t stream) {
  const float* LE = (const float*)d_in[0];
  const float* FZ = (const float*)d_in[1];
  const float* SE = (const float*)d_in[2];
  const float* LM = (const float*)d_in[3];
  const int* labels = (const int*)d_in[4];
  const float* tp = (const float*)d_in[5];
  const float* xip = (const float*)d_in[6];
  float* out = (float*)d_out;

  char* ws = (char*)d_ws;
  unsigned short* An = (unsigned short*)(ws);              // 2 MB
  unsigned short* Fn = (unsigned short*)(ws + 2097152);    // 4 MB
  unsigned short* Sn = (unsigned short*)(ws + 6291456);    // 2 MB
  unsigned short* Ln = (unsigned short*)(ws + 8388608);    // 2 MB
  float2* Pc = (float2*)(ws + 10485760);                   // 1 MB
  float2* Px = (float2*)(ws + 11534336);                   // 4 MB
  float* hacc = (float*)(ws + 15728640);                   // 1
  float* fbuf = hacc + 1;                                  // 48

  norm_kernel<<<dim3(5120), dim3(256), 0, stream>>>(LE, FZ, SE, LM, An, Fn,
                                                    Sn, Ln, hacc);
  // 528 class (tri 32) + 2080 cross (tri 64) + 1024 hash = 3632 blocks
  fused_sim<<<dim3(3632), dim3(256), 0, stream>>>(An, Fn, Sn, Ln, labels, tp,
                                                  xip, Pc, Px, hacc);
  finalize1<<<dim3(48), dim3(256), 0, stream>>>(Pc, Px, fbuf);
  finalize2<<<dim3(1), dim3(64), 0, stream>>>(fbuf, hacc, out);
}

// Round 5
// 166.880 us; speedup vs baseline: 1.2710x; 1.2710x over previous
//
#include <hip/hip_runtime.h>
#include <hip/hip_bf16.h>
#include <stdint.h>

// ---------------------------------------------------------------------------
// Loss_29592324669863, round 5.
//  - norm rows -> bf16 (+ zero-init of out[0..1], hacc)
//  - fused Gram kernel: r3 geometry (128x128 tile, 4 waves, BK=64, 8-granule
//    XOR(row&7) swizzle -> 0 conflicts) + counted-vmcnt double-buffer
//    (vmcnt(8) per step, raw barriers, setprio on MFMA). launch_bounds(256,2)
//    so no VGPR squeeze (r4 lesson: (256,4) -> 64 VGPR -> spill scratch).
//    Epilogue: conflict-free float2 partial slots (no global atomics).
//  - single finalize kernel (48 blocks) -> out[3] via atomicAdd.
// ---------------------------------------------------------------------------

typedef __attribute__((ext_vector_type(8))) short bf16x8;   // 8 bf16 = 4 VGPR
typedef __attribute__((ext_vector_type(4))) float f32x4;

__device__ inline void gload_lds16(const void* g, void* l) {
  __builtin_amdgcn_global_load_lds(
      (__attribute__((address_space(1))) void*)g,
      (__attribute__((address_space(3))) void*)l, 16, 0, 0);
}

__device__ inline void barrier_raw() {
  asm volatile("" ::: "memory");
  __builtin_amdgcn_s_barrier();
  asm volatile("" ::: "memory");
}

__device__ inline unsigned short f2bf(float x) {  // RNE f32->bf16
  unsigned int u = __builtin_bit_cast(unsigned int, x);
  u = (u + 0x7fffu + ((u >> 16) & 1u)) >> 16;
  return (unsigned short)u;
}

// ---------------------------------------------------------------------------
__global__ __launch_bounds__(256) void norm_kernel(
    const float* __restrict__ LE, const float* __restrict__ FZ,
    const float* __restrict__ SE, const float* __restrict__ LM,
    unsigned short* __restrict__ An, unsigned short* __restrict__ Fn,
    unsigned short* __restrict__ Sn, unsigned short* __restrict__ Ln,
    float* __restrict__ hacc, float* __restrict__ out) {
  const int tid = threadIdx.x;
  if (blockIdx.x == 0) {        // zero accumulators for this call
    if (tid == 0) out[0] = 0.f;
    if (tid == 1) out[1] = 0.f;
    if (tid == 2) hacc[0] = 0.f;
  }

  const int wid = tid >> 6, lane = tid & 63;
  const int row = blockIdx.x * 4 + wid;

  const float* src;
  unsigned short* dst;
  int r;
  if (row < 4096)       { src = LE; dst = An; r = row; }
  else if (row < 12288) { src = FZ; dst = Fn; r = row - 4096; }
  else if (row < 16384) { src = SE; dst = Sn; r = row - 12288; }
  else                  { src = LM; dst = Ln; r = row - 16384; }

  const float4 v = *(const float4*)(src + (size_t)r * 256 + lane * 4);
  float ss = v.x * v.x + v.y * v.y + v.z * v.z + v.w * v.w;
#pragma unroll
  for (int m = 1; m < 64; m <<= 1) ss += __shfl_xor(ss, m);
  const float scale = 1.0f / fmaxf(sqrtf(ss), 1e-8f);

  ushort4 o;
  o.x = f2bf(v.x * scale);
  o.y = f2bf(v.y * scale);
  o.z = f2bf(v.z * scale);
  o.w = f2bf(v.w * scale);
  *(ushort4*)(dst + (size_t)r * 256 + lane * 4) = o;
}

// ---------------------------------------------------------------------------
__device__ inline void tri_decode(int t, int nb, int& rb, int& cb) {
  int r = 0;
  while (t >= nb - r) { t -= nb - r; ++r; }
  rb = r;
  cb = r + t;
}

// ---------------------------------------------------------------------------
// Fused Gram kernel: 128x128 tile, 4 waves (2x2), BK=64, dbuf counted-vmcnt.
// LDS rows 128B, 8 granules; phys granule = logical ^ (row&7) applied on the
// pre-swizzled GLOBAL src (LDS write linear) and on ds_read addrs (r3-proven).
// ---------------------------------------------------------------------------
__global__ __launch_bounds__(256, 2) void fused_sim(
    const unsigned short* __restrict__ An, const unsigned short* __restrict__ Fn,
    const unsigned short* __restrict__ Sn, const unsigned short* __restrict__ Ln,
    const int* __restrict__ labels,
    const float* __restrict__ tp, const float* __restrict__ xip,
    float2* __restrict__ Pc,   // [32 slots][4096 rows] (num,den)
    float2* __restrict__ Px,   // [64 slots][8192 rows]
    float* __restrict__ hacc) {
  __shared__ __align__(16) char Ab[2][16384];   // [buf][128 rows x 128B]
  __shared__ __align__(16) char Bb[2][16384];
  __shared__ int lrS[128], lcS[128];

  // XCD swizzle: 3632 = 8 * 454 (bijective)
  const int hw = blockIdx.x;
  const int bid = (hw & 7) * 454 + (hw >> 3);

  int mode, rb, cb;
  const unsigned short *X, *Y;
  if (bid < 528) {            // class: tri over 32x32 panels
    mode = 0; tri_decode(bid, 32, rb, cb); X = An; Y = An;
  } else if (bid < 2608) {    // cross: tri over 64x64 panels
    mode = 1; tri_decode(bid - 528, 64, rb, cb); X = Fn; Y = Fn;
  } else {                    // hash: full 32x32
    mode = 2; const int t = bid - 2608; rb = t >> 5; cb = t & 31;
    X = Sn; Y = Ln;
  }

  const int tid = threadIdx.x;
  const int lane = tid & 63, wid = tid >> 6;
  const int wr = wid >> 1, wc = wid & 1;
  const int g = lane >> 4, c = lane & 15;

  // labels: issue FIRST so vmcnt accounting is {labels, stage0, stage1}
  int mylab = labels[(tid < 128 ? rb * 128 + tid : cb * 128 + tid - 128) & 4095];

  f32x4 acc[4][4];
  const f32x4 zero = {0.f, 0.f, 0.f, 0.f};
#pragma unroll
  for (int m = 0; m < 4; ++m)
#pragma unroll
    for (int n = 0; n < 4; ++n) acc[m][n] = zero;

  // staging geometry (r3-proven): per stage, per thread 4 A + 4 B loads of
  // 16B; rows t*32+srow, LDS linear dest wid*1024 + t*4096 + lane*16.
  const int srow = tid >> 3;                      // 0..31
  const int sgl = (tid & 7) ^ (srow & 7);         // swizzled source granule
  const char* xs = (const char*)X + ((size_t)rb * 128 + srow) * 512 + sgl * 16;
  const char* ys = (const char*)Y + ((size_t)cb * 128 + srow) * 512 + sgl * 16;

#define STAGE(KK, BUF)                                                    \
  do {                                                                    \
    const char* xa = xs + (KK) * 128;                                     \
    const char* ya = ys + (KK) * 128;                                     \
    char* da = (char*)(&Ab[(BUF)][0]) + wid * 1024;                       \
    char* db = (char*)(&Bb[(BUF)][0]) + wid * 1024;                       \
    gload_lds16(xa, da);                                                  \
    gload_lds16(xa + 16384, da + 4096);                                   \
    gload_lds16(xa + 32768, da + 8192);                                   \
    gload_lds16(xa + 49152, da + 12288);                                  \
    gload_lds16(ya, db);                                                  \
    gload_lds16(ya + 16384, db + 4096);                                   \
    gload_lds16(ya + 32768, db + 8192);                                   \
    gload_lds16(ya + 49152, db + 12288);                                  \
  } while (0)

  STAGE(0, 0);
  STAGE(1, 1);
  // pin mylab materialization here: compiler's own waitcnt for it retires
  // only the labels load (oldest), leaving the 16 stage loads in flight.
  asm volatile("" : "+v"(mylab));

  // fragment geometry: row = (wr|wc)*64 + m*16 + c, 128B rows,
  // phys granule = (ks*4+g) ^ (row&7) = (ks*4+g) ^ (c&7)
  const int pxs = c & 7;
  const int aoff = (wr * 64 + c) * 128;
  const int boff = (wc * 64 + c) * 128;

#pragma unroll
  for (int kk = 0; kk < 4; ++kk) {
    if (kk < 3) asm volatile("s_waitcnt vmcnt(8)" ::: "memory");
    else        asm volatile("s_waitcnt vmcnt(0)" ::: "memory");
    barrier_raw();                    // buffer (kk&1) ready for all waves
    if (kk == 0) {                    // park labels for the epilogue
      if (tid < 128) lrS[tid] = mylab;
      else           lcS[tid - 128] = mylab;
    }
    const char* ab = (const char*)(&Ab[kk & 1][0]) + aoff;
    const char* bb = (const char*)(&Bb[kk & 1][0]) + boff;
#pragma unroll
    for (int ks = 0; ks < 2; ++ks) {
      const int px = ((ks * 4 + g) ^ pxs) * 16;
      bf16x8 af[4], bg[4];
#pragma unroll
      for (int m = 0; m < 4; ++m) af[m] = *(const bf16x8*)(ab + m * 2048 + px);
#pragma unroll
      for (int n = 0; n < 4; ++n) bg[n] = *(const bf16x8*)(bb + n * 2048 + px);
      __builtin_amdgcn_s_setprio(1);
#pragma unroll
      for (int m = 0; m < 4; ++m)
#pragma unroll
        for (int n = 0; n < 4; ++n)
          acc[m][n] = __builtin_amdgcn_mfma_f32_16x16x32_bf16(
              af[m], bg[n], acc[m][n], 0, 0, 0);
      __builtin_amdgcn_s_setprio(0);
    }
    barrier_raw();                    // all waves done reading buffer (kk&1)
    if (kk < 2) STAGE(kk + 2, kk & 1);
  }
#undef STAGE

  // ---- epilogue; C/D layout: col = c, row = g*4 + reg ----
  float* sc = (float*)(&Ab[0][0]);    // 4KB scratch overlay (post-barrier)
  if (mode < 2) {
    const float invt = 1.0f / tp[0];
    const bool docol = (rb != cb);
    float2* Pp = (mode == 0) ? Pc : Px;
    const int NR = (mode == 0) ? 4096 : 8192;
    int collab[4];
#pragma unroll
    for (int n = 0; n < 4; ++n) collab[n] = lcS[wc * 64 + n * 16 + c];

    float* rowN = sc, *rowD = sc + 256, *colN = sc + 512, *colD = sc + 768;
    float cn[4] = {0.f, 0.f, 0.f, 0.f}, cd[4] = {0.f, 0.f, 0.f, 0.f};
    float rn[16], rd[16];
#pragma unroll
    for (int m = 0; m < 4; ++m) {
#pragma unroll
      for (int reg = 0; reg < 4; ++reg) {
        const int rlab = lrS[wr * 64 + m * 16 + g * 4 + reg];
        float pn = 0.f, pd = 0.f;
#pragma unroll
        for (int n = 0; n < 4; ++n) {
          float e = __expf(acc[m][n][reg] * invt);
          if (mode == 0) e = fminf(e, 1e10f);
          pd += e;
          const float en = (rlab == collab[n]) ? e : 0.f;
          pn += en;
          cd[n] += e;
          cn[n] += en;
        }
#pragma unroll
        for (int msk = 1; msk < 16; msk <<= 1) {
          pn += __shfl_xor(pn, msk);
          pd += __shfl_xor(pd, msk);
        }
        rn[m * 4 + reg] = pn;
        rd[m * 4 + reg] = pd;
      }
    }
    if (c == 0) {
#pragma unroll
      for (int m = 0; m < 4; ++m)
#pragma unroll
        for (int reg = 0; reg < 4; ++reg) {
          const int rloc = wr * 64 + m * 16 + g * 4 + reg;
          rowN[wc * 128 + rloc] = rn[m * 4 + reg];
          rowD[wc * 128 + rloc] = rd[m * 4 + reg];
        }
    }
#pragma unroll
    for (int n = 0; n < 4; ++n) {
      float a = cn[n], b = cd[n];
      a += __shfl_xor(a, 16); b += __shfl_xor(b, 16);
      a += __shfl_xor(a, 32); b += __shfl_xor(b, 32);
      if (g == 0) {
        colN[wr * 128 + wc * 64 + n * 16 + c] = a;
        colD[wr * 128 + wc * 64 + n * 16 + c] = b;
      }
    }
    __syncthreads();
    // conflict-free partial slots: row-contrib -> slot cb, col -> slot rb
    if (tid < 128) {
      Pp[(size_t)cb * NR + rb * 128 + tid] =
          make_float2(rowN[tid] + rowN[128 + tid], rowD[tid] + rowD[128 + tid]);
    } else if (docol) {
      const int t2 = tid - 128;
      Pp[(size_t)rb * NR + cb * 128 + t2] =
          make_float2(colN[t2] + colN[128 + t2], colD[t2] + colD[128 + t2]);
    }
  } else {
    const float xi = xip[0];
    int collab[4];
#pragma unroll
    for (int n = 0; n < 4; ++n) collab[n] = lcS[wc * 64 + n * 16 + c];
    float part = 0.f;
#pragma unroll
    for (int m = 0; m < 4; ++m)
#pragma unroll
      for (int reg = 0; reg < 4; ++reg) {
        const int rlab = lrS[wr * 64 + m * 16 + g * 4 + reg];
#pragma unroll
        for (int n = 0; n < 4; ++n) {
          const float cs = acc[m][n][reg];
          const float Dm = (1.0f - cs) * 0.5f;
          const float u = fmaxf(xi - Dm, 0.0f);
          part += (rlab == collab[n]) ? Dm * Dm : u * u;
        }
      }
#pragma unroll
    for (int msk = 1; msk < 64; msk <<= 1) part += __shfl_xor(part, msk);
    if (lane == 0) sc[wid] = part;
    __syncthreads();
    if (tid == 0) atomicAdd(hacc, sc[0] + sc[1] + sc[2] + sc[3]);
  }
}

// ---------------------------------------------------------------------------
// finalize: blocks 0..15 class rows, 16..47 cross rows; atomic mean into out.
__global__ __launch_bounds__(256) void finalize_kernel(
    const float2* __restrict__ Pc, const float2* __restrict__ Px,
    const float* __restrict__ hacc, float* __restrict__ out) {
  const int b = blockIdx.x, tid = threadIdx.x;
  const float2* P;
  int nslots, NR, row, oi;
  if (b < 16) { P = Pc; nslots = 32; NR = 4096; row = b * 256 + tid; oi = 0; }
  else { P = Px; nslots = 64; NR = 8192; row = (b - 16) * 256 + tid; oi = 1; }
  float n = 0.f, d = 0.f;
  for (int s = 0; s < nslots; ++s) {
    const float2 v = P[(size_t)s * NR + row];
    n += v.x;
    d += v.y;
  }
  float val = -logf(n / fmaxf(d, 1e-10f));
#pragma unroll
  for (int m = 1; m < 64; m <<= 1) val += __shfl_xor(val, m);
  __shared__ float r[4];
  if ((tid & 63) == 0) r[tid >> 6] = val;
  __syncthreads();
  if (tid == 0) atomicAdd(&out[oi], (r[0] + r[1] + r[2] + r[3]) / (float)NR);
  if (b == 0 && tid == 0) out[2] = hacc[0] * (1.0f / 16777216.0f);
}

// ---------------------------------------------------------------------------
extern "C" void kernel_launch(void* const* d_in, const int* in_sizes, int n_in,
                              void* d_out, int out_size, void* d_ws,
                              size_t ws_size, hipStream_t stream) {
  const float* LE = (const float*)d_in[0];
  const float* FZ = (const float*)d_in[1];
  const float* SE = (const float*)d_in[2];
  const float* LM = (const float*)d_in[3];
  const int* labels = (const int*)d_in[4];
  const float* tp = (const float*)d_in[5];
  const float* xip = (const float*)d_in[6];
  float* out = (float*)d_out;

  char* ws = (char*)d_ws;
  unsigned short* An = (unsigned short*)(ws);              // 2 MB
  unsigned short* Fn = (unsigned short*)(ws + 2097152);    // 4 MB
  unsigned short* Sn = (unsigned short*)(ws + 6291456);    // 2 MB
  unsigned short* Ln = (unsigned short*)(ws + 8388608);    // 2 MB
  float2* Pc = (float2*)(ws + 10485760);                   // 1 MB
  float2* Px = (float2*)(ws + 11534336);                   // 4 MB
  float* hacc = (float*)(ws + 15728640);                   // 1

  norm_kernel<<<dim3(5120), dim3(256), 0, stream>>>(LE, FZ, SE, LM, An, Fn,
                                                    Sn, Ln, hacc, out);
  // 528 class (tri 32) + 2080 cross (tri 64) + 1024 hash = 3632 blocks
  fused_sim<<<dim3(3632), dim3(256), 0, stream>>>(An, Fn, Sn, Ln, labels, tp,
                                                  xip, Pc, Px, hacc);
  finalize_kernel<<<dim3(48), dim3(256), 0, stream>>>(Pc, Px, hacc, out);
}